// Round 11
// baseline (167.568 us; speedup 1.0000x reference)
//
#include <hip/hip_runtime.h>
#include <float.h>
#include <stdint.h>

#define HH 640
#define WW 640
#define KTOP 6
#define CONF 0.3f
#define NTHR 256
#define ROWS_W 16                       // output rows per wave
#define ROWS_B 64                       // per block (4 waves)
#define XBANDS 3
#define XOUT 248                        // output cols per band (lanes 1..62)
#define YBLK (HH / ROWS_B)              // 10
#define TASKS_PER_B (XBANDS * YBLK * 4) // 120 wave-tasks per batch
#define MENT (TASKS_PER_B * KTOP)       // 720
#define CAP 128

__device__ __forceinline__ float4 f4max(float4 a, float4 b) {
    return make_float4(fmaxf(a.x, b.x), fmaxf(a.y, b.y), fmaxf(a.z, b.z), fmaxf(a.w, b.w));
}

// DPP wave-wide lane shifts: pure VALU. old = -inf so edge lanes get max-identity.
__device__ __forceinline__ float dpp_up(float v) {   // lane i <- i-1
    return __int_as_float(__builtin_amdgcn_update_dpp(
        (int)0xFF800000, __float_as_int(v), 0x138, 0xF, 0xF, false));
}
__device__ __forceinline__ float dpp_dn(float v) {   // lane i <- i+1
    return __int_as_float(__builtin_amdgcn_update_dpp(
        (int)0xFF800000, __float_as_int(v), 0x130, 0xF, 0xF, false));
}

// ------- Kernel 1: halo-shared register NMS (1.125x traffic), per-wave top-6 -------
__global__ __launch_bounds__(NTHR, 2) void peaks_kernel(const float* __restrict__ hm,
                                                        float* __restrict__ bscore,
                                                        int* __restrict__ bidx) {
    __shared__ float lds_below[4][4][256];   // halo rows yw0-4..yw0-1 per wave (16 KB)
    __shared__ float lds_above[4][4][256];   // halo rows yw0+16..+19 per wave (16 KB)
    __shared__ float c_score[4][CAP];
    __shared__ int   c_idx[4][CAP];
    __shared__ int   c_cnt[4];

    const int t    = threadIdx.x;
    const int lane = t & 63;
    const int w    = t >> 6;
    const int b    = blockIdx.z;
    const int yb0  = blockIdx.y * ROWS_B;
    const int yw0  = yb0 + w * ROWS_W;
    const int x_raw = blockIdx.x * XOUT - 4 + 4 * lane;
    const int xc    = min(max(x_raw, 0), WW - 4);
    const bool xok  = (x_raw >= 0) && (x_raw <= WW - 4);
    const bool vlane = (lane >= 1) && (lane <= 62) && xok;
    const float* colp = hm + (size_t)b * (HH * WW) + xc;
    const float4 NEG = make_float4(-FLT_MAX, -FLT_MAX, -FLT_MAX, -FLT_MAX);

    if (lane == 0) c_cnt[w] = 0;

    // ---- own 16 rows, asm-batched (plus 4 outer-halo rows on edge waves) ----
    float4 r0, r1, r2, r3, r4, r5, r6, r7, r8, r9, r10, r11, r12, r13, r14, r15;
    float4 e0, e1, e2, e3;   // wave0: rows yw0-4..-1 ; wave3: rows yw0+16..+19
    #define LDA(dst, yy) { int gy = (yy); \
        gy = gy < 0 ? 0 : (gy > HH - 1 ? HH - 1 : gy); \
        const float* ap = colp + (size_t)gy * WW; \
        asm volatile("global_load_dwordx4 %0, %1, off" : "=&v"(dst) : "v"(ap)); }
    LDA(r0,  yw0 + 0)  LDA(r1,  yw0 + 1)  LDA(r2,  yw0 + 2)  LDA(r3,  yw0 + 3)
    LDA(r4,  yw0 + 4)  LDA(r5,  yw0 + 5)  LDA(r6,  yw0 + 6)  LDA(r7,  yw0 + 7)
    LDA(r8,  yw0 + 8)  LDA(r9,  yw0 + 9)  LDA(r10, yw0 + 10) LDA(r11, yw0 + 11)
    LDA(r12, yw0 + 12) LDA(r13, yw0 + 13) LDA(r14, yw0 + 14) LDA(r15, yw0 + 15)
    if (w == 0) { LDA(e0, yw0 - 4)  LDA(e1, yw0 - 3)  LDA(e2, yw0 - 2)  LDA(e3, yw0 - 1) }
    if (w == 3) { LDA(e0, yw0 + 16) LDA(e1, yw0 + 17) LDA(e2, yw0 + 18) LDA(e3, yw0 + 19) }

    asm volatile("s_waitcnt vmcnt(0)" ::: "memory");

    // ---- publish boundary rows to neighbor waves ----
    const int lc = 4 * lane;
    if (w > 0) {  // my rows 0..3 are wave w-1's above-halo
        *reinterpret_cast<float4*>(&lds_above[w - 1][0][lc]) = r0;
        *reinterpret_cast<float4*>(&lds_above[w - 1][1][lc]) = r1;
        *reinterpret_cast<float4*>(&lds_above[w - 1][2][lc]) = r2;
        *reinterpret_cast<float4*>(&lds_above[w - 1][3][lc]) = r3;
    }
    if (w < 3) {  // my rows 12..15 are wave w+1's below-halo
        *reinterpret_cast<float4*>(&lds_below[w + 1][0][lc]) = r12;
        *reinterpret_cast<float4*>(&lds_below[w + 1][1][lc]) = r13;
        *reinterpret_cast<float4*>(&lds_below[w + 1][2][lc]) = r14;
        *reinterpret_cast<float4*>(&lds_below[w + 1][3][lc]) = r15;
    }
    if (w == 0) {
        *reinterpret_cast<float4*>(&lds_below[0][0][lc]) = e0;
        *reinterpret_cast<float4*>(&lds_below[0][1][lc]) = e1;
        *reinterpret_cast<float4*>(&lds_below[0][2][lc]) = e2;
        *reinterpret_cast<float4*>(&lds_below[0][3][lc]) = e3;
    }
    if (w == 3) {
        *reinterpret_cast<float4*>(&lds_above[3][0][lc]) = e0;
        *reinterpret_cast<float4*>(&lds_above[3][1][lc]) = e1;
        *reinterpret_cast<float4*>(&lds_above[3][2][lc]) = e2;
        *reinterpret_cast<float4*>(&lds_above[3][3][lc]) = e3;
    }
    __syncthreads();

    const float4 b0 = *reinterpret_cast<const float4*>(&lds_below[w][0][lc]);
    const float4 b1 = *reinterpret_cast<const float4*>(&lds_below[w][1][lc]);
    const float4 b2 = *reinterpret_cast<const float4*>(&lds_below[w][2][lc]);
    const float4 b3 = *reinterpret_cast<const float4*>(&lds_below[w][3][lc]);
    const float4 a0 = *reinterpret_cast<const float4*>(&lds_above[w][0][lc]);
    const float4 a1 = *reinterpret_cast<const float4*>(&lds_above[w][1][lc]);
    const float4 a2 = *reinterpret_cast<const float4*>(&lds_above[w][2][lc]);
    const float4 a3 = *reinterpret_cast<const float4*>(&lds_above[w][3][lc]);

    // horizontal 9-max via DPP + peak detect (4 output px per lane per row)
    #define PROCROW(m, c, gy_) { \
        const float a_ = fmaxf(m.y, m.z); \
        const float w0 = dpp_up(m.x), ha = dpp_up(a_), w2 = dpp_up(m.z), w3 = dpp_up(m.w); \
        const float w8 = dpp_dn(m.x), w9 = dpp_dn(m.y), hb = dpp_dn(a_), wB = dpp_dn(m.w); \
        const float mc = fmaxf(fmaxf(m.x, a_), m.w); \
        const float hc = fmaxf(fmaxf(w3, mc), w8); \
        const float h0 = fmaxf(hc, fmaxf(w0, ha)); \
        const float h1 = fmaxf(hc, fmaxf(ha, w9)); \
        const float h2 = fmaxf(hc, fmaxf(w2, hb)); \
        const float h3 = fmaxf(hc, fmaxf(hb, wB)); \
        if (vlane) { \
            const int base = (gy_) * WW + x_raw; \
            if (c.x > CONF && c.x >= h0) { int p_ = atomicAdd(&c_cnt[w], 1); if (p_ < CAP) { c_score[w][p_] = c.x; c_idx[w][p_] = base;     } } \
            if (c.y > CONF && c.y >= h1) { int p_ = atomicAdd(&c_cnt[w], 1); if (p_ < CAP) { c_score[w][p_] = c.y; c_idx[w][p_] = base + 1; } } \
            if (c.z > CONF && c.z >= h2) { int p_ = atomicAdd(&c_cnt[w], 1); if (p_ < CAP) { c_score[w][p_] = c.z; c_idx[w][p_] = base + 2; } } \
            if (c.w > CONF && c.w >= h3) { int p_ = atomicAdd(&c_cnt[w], 1); if (p_ < CAP) { c_score[w][p_] = c.w; c_idx[w][p_] = base + 3; } } \
        } \
    }
    #define VROW(Sx, c, gy_) { \
        float4 m = f4max(Sx, pref); \
        if (!xok) m = NEG; \
        PROCROW(m, c, gy_) \
    }

    // ---- chunk A: output rows 0..7 (inputs b0..b3, r0..r11) ----
    {
        float4 S7 = r3;
        float4 S6 = f4max(r2, S7), S5 = f4max(r1, S6), S4 = f4max(r0, S5);
        float4 S3 = f4max(b3, S4), S2 = f4max(b2, S3), S1 = f4max(b1, S2), S0 = f4max(b0, S1);
        float4 pref = r4;
        VROW(S0, r0, yw0 + 0)  pref = f4max(pref, r5);
        VROW(S1, r1, yw0 + 1)  pref = f4max(pref, r6);
        VROW(S2, r2, yw0 + 2)  pref = f4max(pref, r7);
        VROW(S3, r3, yw0 + 3)  pref = f4max(pref, r8);
        VROW(S4, r4, yw0 + 4)  pref = f4max(pref, r9);
        VROW(S5, r5, yw0 + 5)  pref = f4max(pref, r10);
        VROW(S6, r6, yw0 + 6)  pref = f4max(pref, r11);
        VROW(S7, r7, yw0 + 7)
    }
    // ---- chunk B: output rows 8..15 (inputs r4..r15, a0..a3) ----
    {
        float4 S7 = r11;
        float4 S6 = f4max(r10, S7), S5 = f4max(r9, S6), S4 = f4max(r8, S5);
        float4 S3 = f4max(r7, S4), S2 = f4max(r6, S3), S1 = f4max(r5, S2), S0 = f4max(r4, S1);
        float4 pref = r12;
        VROW(S0, r8,  yw0 + 8)   pref = f4max(pref, r13);
        VROW(S1, r9,  yw0 + 9)   pref = f4max(pref, r14);
        VROW(S2, r10, yw0 + 10)  pref = f4max(pref, r15);
        VROW(S3, r11, yw0 + 11)  pref = f4max(pref, a0);
        VROW(S4, r12, yw0 + 12)  pref = f4max(pref, a1);
        VROW(S5, r13, yw0 + 13)  pref = f4max(pref, a2);
        VROW(S6, r14, yw0 + 14)  pref = f4max(pref, a3);
        VROW(S7, r15, yw0 + 15)
    }

    // ---- per-wave top-6 from own LDS list (wave-private) ----
    {
        const int cnt = min(c_cnt[w], CAP);
        float cs0 = (lane      < cnt) ? c_score[w][lane]      : -2.0f;
        int   ci0 = (lane      < cnt) ? c_idx[w][lane]        : 0x7fffffff;
        float cs1 = (lane + 64 < cnt) ? c_score[w][lane + 64] : -2.0f;
        int   ci1 = (lane + 64 < cnt) ? c_idx[w][lane + 64]   : 0x7fffffff;
        const int outbase = ((b * YBLK + blockIdx.y) * 4 + w) * XBANDS * KTOP
                            + blockIdx.x * KTOP;
        #pragma unroll
        for (int k = 0; k < KTOP; ++k) {
            float bs; int bi;
            if (cs0 > cs1 || (cs0 == cs1 && ci0 < ci1)) { bs = cs0; bi = ci0; }
            else                                        { bs = cs1; bi = ci1; }
            #pragma unroll
            for (int off = 32; off >= 1; off >>= 1) {
                const float os = __shfl_xor(bs, off);
                const int   oi = __shfl_xor(bi, off);
                if (os > bs || (os == bs && oi < bi)) { bs = os; bi = oi; }
            }
            if (lane == 0) { bscore[outbase + k] = bs; bidx[outbase + k] = bi; }
            if (ci0 == bi) cs0 = -3.0f;
            if (ci1 == bi) cs1 = -3.0f;
        }
    }
}

// ------- Kernel 2: per-batch merge of 720 entries -> top-6 (1 wave) -------
__global__ __launch_bounds__(64) void topk_kernel(const float* __restrict__ bscore,
                                                  const int* __restrict__ bidx,
                                                  float* __restrict__ out,
                                                  int B) {
    const int t = threadIdx.x;   // 64 threads
    const int b = blockIdx.x;

    float s[12]; int id[12];
    #pragma unroll
    for (int j = 0; j < 12; ++j) {
        const int e = t + 64 * j;
        const bool ok = e < MENT;
        s[j]  = ok ? bscore[b * MENT + e] : -9.0f;
        id[j] = ok ? bidx[b * MENT + e]   : 0x7fffffff;
    }

    float my_s = -9.0f; int my_i = 0x7fffffff;
    #pragma unroll
    for (int k = 0; k < KTOP; ++k) {
        float bs = s[0]; int bi = id[0];
        #pragma unroll
        for (int j = 1; j < 12; ++j)
            if (s[j] > bs || (s[j] == bs && id[j] < bi)) { bs = s[j]; bi = id[j]; }
        #pragma unroll
        for (int off = 32; off >= 1; off >>= 1) {
            const float os = __shfl_xor(bs, off);
            const int   oi = __shfl_xor(bi, off);
            if (os > bs || (os == bs && oi < bi)) { bs = os; bi = oi; }
        }
        if (t == k) { my_s = bs; my_i = bi; }   // thread k owns result k
        #pragma unroll
        for (int j = 0; j < 12; ++j) if (id[j] == bi) s[j] = -9.0f;
    }

    if (t < KTOP) {
        const bool valid = (my_s > CONF) && (my_i >= 0) && (my_i < HH * WW);
        const int idv = valid ? my_i : 0;
        const int xi = idv % WW;
        const int yi = idv / WW;
        const float px = valid ? xi * (1.0f / (WW - 1)) : -1.0f;
        const float py = valid ? yi * (1.0f / (HH - 1)) : -1.0f;
        out[(size_t)b * KTOP * 2 + t * 2 + 0] = px;
        out[(size_t)b * KTOP * 2 + t * 2 + 1] = py;
        out[(size_t)B * KTOP * 2 + (size_t)b * KTOP + t] = valid ? my_s : 0.0f;
    }
}

extern "C" void kernel_launch(void* const* d_in, const int* in_sizes, int n_in,
                              void* d_out, int out_size, void* d_ws, size_t ws_size,
                              hipStream_t stream) {
    const float* hm = (const float*)d_in[0];
    float* out = (float*)d_out;
    const int B = in_sizes[0] / (HH * WW);

    float* bscore = (float*)d_ws;
    int*   bidx   = (int*)((char*)d_ws + sizeof(float) * (size_t)B * MENT);

    dim3 grid1(XBANDS, YBLK, B);   // 3 x 10 x 64 = 1920 blocks of 4 waves
    peaks_kernel<<<grid1, NTHR, 0, stream>>>(hm, bscore, bidx);
    topk_kernel<<<B, 64, 0, stream>>>(bscore, bidx, out, B);
}